// Round 8
// baseline (852.691 us; speedup 1.0000x reference)
//
#include <hip/hip_runtime.h>
#include <math.h>

#define NA 512
#define NN (NA*NA)
#define COULOMB 14.399645478425668f
#define SQRT_PI 1.7724538509055160273f

__device__ __forceinline__ float rl(float x, int lane) {
    return __int_as_float(__builtin_amdgcn_readlane(__float_as_int(x), lane));
}

__device__ __forceinline__ float pair_val(float dx, float dy, float dz,
                                          float s2i, float s2k) {
    float d2 = dx*dx + dy*dy + dz*dz;
    float rinv = rsqrtf(d2);
    return COULOMB * erff(d2 * rinv * rsqrtf(2.f * (s2i + s2k))) * rinv;
}

// ---------------------------------------------------------------- K1: per-atom
__global__ void k_pre(const float* __restrict__ feats, const float* __restrict__ w,
                      const int* __restrict__ type, const float* __restrict__ hard,
                      const float* __restrict__ sigma,
                      float* __restrict__ chi, float* __restrict__ diag,
                      float* __restrict__ sigA, int N) {
    __shared__ float wl[64];
    int tid = threadIdx.x;
    if (tid < 64) wl[tid] = w[tid];
    __syncthreads();
    int i = blockIdx.x * 256 + tid;
    if (i >= N) return;
    const float4* fp = (const float4*)(feats + (size_t)i * 64);
    float acc = 0.f;
#pragma unroll
    for (int q = 0; q < 16; q++) {
        float4 v = fp[q];
        acc += v.x * wl[4*q] + v.y * wl[4*q+1] + v.z * wl[4*q+2] + v.w * wl[4*q+3];
    }
    chi[i] = acc;
    int t = type[i];
    float s = sigma[t];
    float h = hard[t];
    sigA[i] = s;
    diag[i] = h * h + COULOMB / (SQRT_PI * s);
}

// ------------------------------------------- K2: diag factor + split panel trsm (j=0..4)
__global__ void __launch_bounds__(256, 1) k_panel(const float* __restrict__ pos,
                                                  const float* __restrict__ sigA,
                                                  const float* __restrict__ diagA,
                                                  float* __restrict__ C, const int j) {
    const int q = blockIdx.x;
    const int b = blockIdx.y;
    float* __restrict__ Cb = C + (size_t)b * NN;
    const int jb = j * 64;
    const int m = NA - jb - 64;
    const int tid = threadIdx.x;
    __shared__ float D[64 * 65];
    __shared__ float DT[64 * 64];
    __shared__ float invd[64];
    __shared__ float px[NA], py[NA], pz[NA], s2s[NA];

    if (j == 0) {
#pragma unroll
        for (int e = 0; e < 2; e++) {
            int i = e * 256 + tid;
            px[i] = pos[((size_t)b * NA + i) * 3 + 0];
            py[i] = pos[((size_t)b * NA + i) * 3 + 1];
            pz[i] = pos[((size_t)b * NA + i) * 3 + 2];
            float s = sigA[b * NA + i];
            s2s[i] = s * s;
        }
        __syncthreads();
    }

#pragma unroll
    for (int e = 0; e < 16; e++) {
        int f = e * 256 + tid;
        int rr = f >> 6, cc = f & 63;
        float v;
        if (j == 0) {
            if (rr == cc) v = diagA[b * NA + rr];
            else v = pair_val(px[rr]-px[cc], py[rr]-py[cc], pz[rr]-pz[cc], s2s[rr], s2s[cc]);
        } else {
            v = Cb[(size_t)(jb + rr) * NA + jb + cc];
        }
        D[rr * 65 + cc] = v;
    }

    const int h = m >> 1;
    const int r0 = q ? h : 0;
    const int nr = q ? (m - h) : h;
    const int r = tid - 32;
    const bool hasrow = (r >= 0 && r < nr);
    const int grow = jb + 64 + r0 + r;
    float rv[64];
    if (hasrow) {
        if (j == 0) {
#pragma unroll
            for (int k = 0; k < 64; k++)
                rv[k] = pair_val(px[grow]-px[k], py[grow]-py[k], pz[grow]-pz[k],
                                 s2s[grow], s2s[k]);
        } else {
            const float4* rp = (const float4*)(Cb + (size_t)grow * NA + jb);
#pragma unroll
            for (int qq = 0; qq < 16; qq++) {
                float4 v = rp[qq];
                rv[4*qq] = v.x; rv[4*qq+1] = v.y; rv[4*qq+2] = v.z; rv[4*qq+3] = v.w;
            }
        }
    }
    __syncthreads();

    if (tid < 64) {
        const int t = tid;
        float cl[64];
#pragma unroll
        for (int i = 0; i < 64; i++) cl[i] = (i >= t) ? D[i * 65 + t] : D[t * 65 + i];
#pragma unroll
        for (int k = 0; k < 64; k++) {
            float pivot = rl(cl[k], k);
            float invp = 1.0f / pivot;
            float factor = (t > k) ? (cl[k] * invp) : 0.0f;
#pragma unroll
            for (int i = k + 1; i < 64; i++) {
                float bc = rl(cl[i], k);
                cl[i] -= bc * factor;
            }
        }
        float rs = 1.0f / sqrtf(cl[t]);
        invd[t] = rs;
#pragma unroll
        for (int i = 0; i < 64; i++)
            if (i >= t) D[i * 65 + t] = cl[i] * rs;
    }
    __syncthreads();

#pragma unroll
    for (int e = 0; e < 16; e++) {
        int f = e * 256 + tid;
        int row = f >> 6, cc = f & 63;
        float v = D[row * 65 + cc];
        DT[row * 64 + cc] = (cc < row) ? v : 0.f;
        if (q == 0 && cc <= row) Cb[(size_t)(jb + row) * NA + jb + cc] = v;
    }
    __syncthreads();

    if (hasrow) {
#pragma unroll
        for (int k = 0; k < 64; k++) {
            float acc = rv[k];
            const float4* Lr = (const float4*)(DT + k * 64);
            const int k4 = k >> 2;
#pragma unroll
            for (int t4 = 0; t4 < k4; t4++) {
                float4 Lv = Lr[t4];
                acc -= Lv.x * rv[4*t4] + Lv.y * rv[4*t4+1] + Lv.z * rv[4*t4+2] + Lv.w * rv[4*t4+3];
            }
#pragma unroll
            for (int tt = k4 * 4; tt < k; tt++) acc -= DT[k * 64 + tt] * rv[tt];
            rv[k] = acc * invd[k];
        }
        float4* rp = (float4*)(Cb + (size_t)grow * NA + jb);
#pragma unroll
        for (int qq = 0; qq < 16; qq++)
            rp[qq] = make_float4(rv[4*qq], rv[4*qq+1], rv[4*qq+2], rv[4*qq+3]);
    }
}

// ------------------------------------------- K3: trailing update (j=0..4) — round-3 proven
template<bool GEN>
__global__ void __launch_bounds__(256, 3) k_trail(float* __restrict__ C,
                                                  const float* __restrict__ pos,
                                                  const float* __restrict__ sigA,
                                                  const float* __restrict__ diagA,
                                                  const int j) {
    const int b = blockIdx.y;
    float* __restrict__ Cb = C + (size_t)b * NN;
    const int jb = j * 64;
    const int m = NA - jb - 64;
    int t = blockIdx.x;
    int RI = 0;
    while (t >= RI + 1) { t -= RI + 1; RI++; }
    const int RJ = t;
    const int RB = RI * 128, CB = RJ * 128;
    const int vr = min(128, m - RB);
    const int vc = min(128, m - CB);
    const int tid = threadIdx.x;
    const int rg = tid >> 4, cg = tid & 15;

    __shared__ float As[128 * 65];
    __shared__ float Bs[128 * 65];

    float acc[8][8];

    if (GEN) {
        __shared__ float pAx[128], pAy[128], pAz[128], sA[128], dA[128];
        __shared__ float pBx[128], pBy[128], pBz[128], sB[128];
        if (tid < 128) {
            if (RB + tid < m) {
                int ga = b * NA + jb + 64 + RB + tid;
                pAx[tid] = pos[(size_t)ga * 3 + 0];
                pAy[tid] = pos[(size_t)ga * 3 + 1];
                pAz[tid] = pos[(size_t)ga * 3 + 2];
                float s = sigA[ga]; sA[tid] = s * s;
                dA[tid] = diagA[ga];
            }
        } else {
            int u = tid - 128;
            if (CB + u < m) {
                int gb = b * NA + jb + 64 + CB + u;
                pBx[u] = pos[(size_t)gb * 3 + 0];
                pBy[u] = pos[(size_t)gb * 3 + 1];
                pBz[u] = pos[(size_t)gb * 3 + 2];
                float s = sigA[gb]; sB[u] = s * s;
            }
        }
        __syncthreads();
#pragma unroll
        for (int rr = 0; rr < 8; rr++) {
            int row = rg * 8 + rr;
#pragma unroll
            for (int cc = 0; cc < 8; cc++) {
                int col = cg + 16 * cc;
                if (RB + row == CB + col)
                    acc[rr][cc] = dA[row];
                else
                    acc[rr][cc] = pair_val(pAx[row]-pBx[col], pAy[row]-pBy[col],
                                           pAz[row]-pBz[col], sA[row], sB[col]);
            }
        }
        __syncthreads();
    } else {
        const int GRB = jb + 64 + RB, GCB = jb + 64 + CB;
#pragma unroll
        for (int rr = 0; rr < 8; rr++) {
            int row = rg * 8 + rr;
#pragma unroll
            for (int cc = 0; cc < 8; cc++) {
                int col = cg + 16 * cc;
                acc[rr][cc] = (row < vr && col < vc)
                    ? Cb[(size_t)(GRB + row) * NA + GCB + col] : 0.f;
            }
        }
    }

    const float* Pan = Cb + (size_t)(jb + 64) * NA + jb;
#pragma unroll
    for (int e = 0; e < 8; e++) {
        int f = e * 256 + tid;
        int row = f >> 4, s = f & 15;
        float4 v = make_float4(0.f, 0.f, 0.f, 0.f);
        if (row < vr) v = *(const float4*)(Pan + (size_t)(RB + row) * NA + s * 4);
        As[row * 65 + s * 4 + 0] = v.x;
        As[row * 65 + s * 4 + 1] = v.y;
        As[row * 65 + s * 4 + 2] = v.z;
        As[row * 65 + s * 4 + 3] = v.w;
        float4 u = make_float4(0.f, 0.f, 0.f, 0.f);
        if (row < vc) u = *(const float4*)(Pan + (size_t)(CB + row) * NA + s * 4);
        Bs[row * 65 + s * 4 + 0] = u.x;
        Bs[row * 65 + s * 4 + 1] = u.y;
        Bs[row * 65 + s * 4 + 2] = u.z;
        Bs[row * 65 + s * 4 + 3] = u.w;
    }
    __syncthreads();

#pragma unroll 4
    for (int k = 0; k < 64; k++) {
        float ai[8], bj[8];
#pragma unroll
        for (int rr = 0; rr < 8; rr++) ai[rr] = As[(rg * 8 + rr) * 65 + k];
#pragma unroll
        for (int cc = 0; cc < 8; cc++) bj[cc] = Bs[(cg + 16 * cc) * 65 + k];
#pragma unroll
        for (int rr = 0; rr < 8; rr++)
#pragma unroll
            for (int cc = 0; cc < 8; cc++)
                acc[rr][cc] = fmaf(-ai[rr], bj[cc], acc[rr][cc]);
    }

    const int GRB = jb + 64 + RB, GCB = jb + 64 + CB;
#pragma unroll
    for (int rr = 0; rr < 8; rr++) {
        int row = rg * 8 + rr;
        if (row < vr) {
#pragma unroll
            for (int cc = 0; cc < 8; cc++) {
                int col = cg + 16 * cc;
                if (col < vc)
                    Cb[(size_t)(GRB + row) * NA + GCB + col] = acc[rr][cc];
            }
        }
    }
}

// ------------------------------------------- K4: LDS-resident tail (j=5,6,7; 192x192)
// One block/molecule, 512 thr. The whole 192x192 tail lives in LDS (stride 193:
// trsm row/col accesses land 2-way per bank = free; Ljj reads are uniform
// broadcasts). Load once, 3 factor/trsm/update rounds at LDS latency, store once.
// gfx950 LDS = 160 KiB per workgroup; T = 148.2 KB static.
#define TS 193
__global__ void __launch_bounds__(512, 1) k_tail(float* __restrict__ C) {
    const int b = blockIdx.x;
    float* __restrict__ Cb = C + (size_t)b * NN;
    const int base = NA - 192;      // 320
    const int tid = threadIdx.x;
    __shared__ float T[192 * TS];   // 148,224 B
    __shared__ float invd[64];

    // ---- load tail block (rows/cols base..511), coalesced float4
    for (int f = tid; f < 192 * 48; f += 512) {
        int lr = f / 48, lc4 = f % 48;
        float4 v = *(const float4*)(Cb + (size_t)(base + lr) * NA + base + lc4 * 4);
        T[lr * TS + lc4 * 4 + 0] = v.x;
        T[lr * TS + lc4 * 4 + 1] = v.y;
        T[lr * TS + lc4 * 4 + 2] = v.z;
        T[lr * TS + lc4 * 4 + 3] = v.w;
    }
    __syncthreads();

    for (int t = 0; t < 3; t++) {
        const int j0 = t * 64;
        const int mrem = 128 - t * 64;      // 128, 64, 0

        // ---- factor 64x64 diag tile (wave 0, register-resident)
        if (tid < 64) {
            const int tt = tid;
            float cl[64];
#pragma unroll
            for (int i = 0; i < 64; i++)
                cl[i] = (i >= tt) ? T[(j0 + i) * TS + j0 + tt]
                                  : T[(j0 + tt) * TS + j0 + i];
#pragma unroll
            for (int k = 0; k < 64; k++) {
                float pivot = rl(cl[k], k);
                float invp = 1.0f / pivot;
                float factor = (tt > k) ? (cl[k] * invp) : 0.0f;
#pragma unroll
                for (int i = k + 1; i < 64; i++) {
                    float bc = rl(cl[i], k);
                    cl[i] -= bc * factor;
                }
            }
            float rs = 1.0f / sqrtf(cl[tt]);
            invd[tt] = rs;
#pragma unroll
            for (int i = 0; i < 64; i++)
                if (i >= tt) T[(j0 + i) * TS + j0 + tt] = cl[i] * rs;
        }
        __syncthreads();
        if (mrem == 0) break;

        // ---- trsm: threads 64..64+mrem own panel rows (all in LDS)
        const int r = tid - 64;
        if (r >= 0 && r < mrem) {
            const int lr = j0 + 64 + r;
            float rv[64];
#pragma unroll
            for (int k = 0; k < 64; k++) rv[k] = T[lr * TS + j0 + k];
#pragma unroll
            for (int k = 0; k < 64; k++) {
                float acc = rv[k];
                const float* Lk = T + (j0 + k) * TS + j0;   // uniform broadcast reads
#pragma unroll 4
                for (int tt = 0; tt < k; tt++) acc -= Lk[tt] * rv[tt];
                rv[k] = acc * invd[k];
            }
#pragma unroll
            for (int k = 0; k < 64; k++) T[lr * TS + j0 + k] = rv[k];
        }
        __syncthreads();

        // ---- rank-64 update of trailing mrem x mrem block (in LDS)
        if (mrem == 128) {
            const int rg = tid >> 5, cg = tid & 31;     // 16 x 32
            const int r0 = j0 + 64 + rg * 8, c0 = j0 + 64 + cg * 4;
            float acc[8][4];
#pragma unroll
            for (int rr = 0; rr < 8; rr++)
#pragma unroll
                for (int cc = 0; cc < 4; cc++)
                    acc[rr][cc] = T[(r0 + rr) * TS + c0 + cc];
#pragma unroll 4
            for (int k = 0; k < 64; k++) {
                float a[8], bb[4];
#pragma unroll
                for (int rr = 0; rr < 8; rr++) a[rr] = T[(r0 + rr) * TS + j0 + k];
#pragma unroll
                for (int cc = 0; cc < 4; cc++) bb[cc] = T[(c0 + cc) * TS + j0 + k];
#pragma unroll
                for (int rr = 0; rr < 8; rr++)
#pragma unroll
                    for (int cc = 0; cc < 4; cc++)
                        acc[rr][cc] = fmaf(-a[rr], bb[cc], acc[rr][cc]);
            }
            __syncthreads();
#pragma unroll
            for (int rr = 0; rr < 8; rr++)
#pragma unroll
                for (int cc = 0; cc < 4; cc++)
                    T[(r0 + rr) * TS + c0 + cc] = acc[rr][cc];
        } else {  // mrem == 64
            const int rg = tid >> 6, col = tid & 63;    // 8 x 64
            const int r0 = j0 + 64 + rg * 8, c = j0 + 64 + col;
            float acc[8];
#pragma unroll
            for (int rr = 0; rr < 8; rr++) acc[rr] = T[(r0 + rr) * TS + c];
#pragma unroll 4
            for (int k = 0; k < 64; k++) {
                float bv = T[c * TS + j0 + k];
#pragma unroll
                for (int rr = 0; rr < 8; rr++)
                    acc[rr] = fmaf(-T[(r0 + rr) * TS + j0 + k], bv, acc[rr]);
            }
            __syncthreads();
#pragma unroll
            for (int rr = 0; rr < 8; rr++) T[(r0 + rr) * TS + c] = acc[rr];
        }
        __syncthreads();
    }

    // ---- store tail back (lower = L; upper garbage unread), coalesced float4
    for (int f = tid; f < 192 * 48; f += 512) {
        int lr = f / 48, lc4 = f % 48;
        float4 v = make_float4(T[lr * TS + lc4 * 4 + 0], T[lr * TS + lc4 * 4 + 1],
                               T[lr * TS + lc4 * 4 + 2], T[lr * TS + lc4 * 4 + 3]);
        *(float4*)(Cb + (size_t)(base + lr) * NA + base + lc4 * 4) = v;
    }
}

// ------------------------------------------- K5: solve + outputs (round-4 proven)
__global__ void __launch_bounds__(512, 1) k_solve(const float* __restrict__ C,
                                                  const float* __restrict__ chiA,
                                                  const float* __restrict__ Qtot,
                                                  float* __restrict__ out, int B) {
    int b = blockIdx.x;
    const float* Cb = C + (size_t)b * NN;
    int tid = threadIdx.x;
    __shared__ float D[64 * 65];
    __shared__ float r1[NA], r2[NA];
    __shared__ float pb1[4][NA], pb2[4][NA];
    __shared__ float red[16];
    __shared__ float muS;

    r1[tid] = chiA[b * NA + tid];
    r2[tid] = 1.0f;

    const int sub = tid & 7;
    const int rowg = tid >> 3;

    for (int j = 0; j < 8; j++) {
        const int jb = j * 64;
        __syncthreads();
#pragma unroll
        for (int e = 0; e < 8; e++) {
            int f = e * 512 + tid;
            int row = f >> 6, cc = f & 63;
            D[row * 65 + cc] = Cb[(size_t)(jb + row) * NA + jb + cc];
        }
        __syncthreads();
        if (tid < 128) {
            int lane = tid & 63;
            float* vv = (tid < 64) ? r1 : r2;
            float val = vv[jb + lane];
            float idg = 1.0f / D[lane * 65 + lane];
#pragma unroll
            for (int k = 0; k < 64; k++) {
                float yk = rl(val, k) * rl(idg, k);
                if (lane == k) vv[jb + k] = yk;
                float lv = (lane > k) ? D[lane * 65 + k] : 0.f;
                val -= lv * yk;
            }
        }
        __syncthreads();
#pragma unroll
        for (int p = 0; p < 7; p++) {
            int g = jb + 64 + p * 64 + rowg;
            if (g < NA) {
                const float4* Lr = (const float4*)(Cb + (size_t)g * NA + jb + sub * 8);
                float4 a0 = Lr[0], a1 = Lr[1];
                int y0 = jb + sub * 8;
                float d1 = a0.x*r1[y0]   + a0.y*r1[y0+1] + a0.z*r1[y0+2] + a0.w*r1[y0+3]
                         + a1.x*r1[y0+4] + a1.y*r1[y0+5] + a1.z*r1[y0+6] + a1.w*r1[y0+7];
                float d2 = a0.x*r2[y0]   + a0.y*r2[y0+1] + a0.z*r2[y0+2] + a0.w*r2[y0+3]
                         + a1.x*r2[y0+4] + a1.y*r2[y0+5] + a1.z*r2[y0+6] + a1.w*r2[y0+7];
                d1 += __shfl_xor(d1, 1); d2 += __shfl_xor(d2, 1);
                d1 += __shfl_xor(d1, 2); d2 += __shfl_xor(d2, 2);
                d1 += __shfl_xor(d1, 4); d2 += __shfl_xor(d2, 4);
                if (sub == 0) { r1[g] -= d1; r2[g] -= d2; }
            }
        }
    }

    const int ii = tid & 127;
    const int gg = tid >> 7;
    for (int j = 7; j >= 0; j--) {
        const int jb = j * 64;
        __syncthreads();
#pragma unroll
        for (int e = 0; e < 8; e++) {
            int f = e * 512 + tid;
            int row = f >> 6, cc = f & 63;
            D[row * 65 + cc] = Cb[(size_t)(jb + row) * NA + jb + cc];
        }
        __syncthreads();
        if (tid < 128) {
            int lane = tid & 63;
            float* vv = (tid < 64) ? r1 : r2;
            float val = vv[jb + lane];
            float idg = 1.0f / D[lane * 65 + lane];
#pragma unroll
            for (int k = 63; k >= 0; k--) {
                float xk = rl(val, k) * rl(idg, k);
                if (lane == k) vv[jb + k] = xk;
                float lv = (lane < k) ? D[k * 65 + lane] : 0.f;
                val -= lv * xk;
            }
        }
        __syncthreads();
        if (jb > 0) {
            const int nf4 = jb >> 2;
            float4 s1 = make_float4(0.f,0.f,0.f,0.f), s2 = make_float4(0.f,0.f,0.f,0.f);
            if (ii < nf4) {
#pragma unroll
                for (int gq = 0; gq < 16; gq++) {
                    int g = jb + gg * 16 + gq;
                    float x1 = r1[g], x2 = r2[g];
                    float4 Lv = *(const float4*)(Cb + (size_t)g * NA + ii * 4);
                    s1.x += Lv.x * x1; s1.y += Lv.y * x1; s1.z += Lv.z * x1; s1.w += Lv.w * x1;
                    s2.x += Lv.x * x2; s2.y += Lv.y * x2; s2.z += Lv.z * x2; s2.w += Lv.w * x2;
                }
            }
            *(float4*)(&pb1[gg][ii * 4]) = s1;
            *(float4*)(&pb2[gg][ii * 4]) = s2;
            __syncthreads();
            if (tid < jb) {
                r1[tid] -= pb1[0][tid] + pb1[1][tid] + pb1[2][tid] + pb1[3][tid];
                r2[tid] -= pb2[0][tid] + pb2[1][tid] + pb2[2][tid] + pb2[3][tid];
            }
        }
    }
    __syncthreads();

    float s1p = r1[tid], s2p = r2[tid];
#pragma unroll
    for (int off = 1; off < 64; off <<= 1) {
        s1p += __shfl_xor(s1p, off);
        s2p += __shfl_xor(s2p, off);
    }
    if ((tid & 63) == 0) { red[tid >> 6] = s1p; red[8 + (tid >> 6)] = s2p; }
    __syncthreads();
    if (tid == 0) {
        float s1 = 0.f, s2 = 0.f;
#pragma unroll
        for (int wv = 0; wv < 8; wv++) { s1 += red[wv]; s2 += red[8 + wv]; }
        muS = -(Qtot[b] + s1) / s2;
    }
    __syncthreads();
    float mu = muS;
    float qv = -r1[tid] - mu * r2[tid];
    out[B + (size_t)b * NA + tid] = qv;

    float eacc = chiA[b * NA + tid] * qv;
#pragma unroll
    for (int off = 1; off < 64; off <<= 1) eacc += __shfl_xor(eacc, off);
    __syncthreads();
    if ((tid & 63) == 0) red[tid >> 6] = eacc;
    __syncthreads();
    if (tid == 0) {
        float e = 0.f;
#pragma unroll
        for (int wv = 0; wv < 8; wv++) e += red[wv];
        out[b] = 0.5f * e - 0.5f * mu * Qtot[b];
    }
}

// ---------------------------------------------------------------- host launch
extern "C" void kernel_launch(void* const* d_in, const int* in_sizes, int n_in,
                              void* d_out, int out_size, void* d_ws, size_t ws_size,
                              hipStream_t stream) {
    const int B = in_sizes[3];          // 128 molecules
    const int N = in_sizes[2];          // 65536 atoms
    const float* feats = (const float*)d_in[0];
    const float* pos   = (const float*)d_in[1];
    const int*   type  = (const int*)d_in[2];
    const float* Qt    = (const float*)d_in[3];
    const float* w     = (const float*)d_in[4];
    const float* hard  = (const float*)d_in[5];
    const float* sig   = (const float*)d_in[6];
    float* out = (float*)d_out;
    float* ws  = (float*)d_ws;

    float* C    = ws;                       // B * 512 * 512
    float* chi  = ws + (size_t)B * NN;      // N
    float* diag = chi + N;                  // N
    float* sigA = diag + N;                 // N

    k_pre<<<(N + 255) / 256, 256, 0, stream>>>(feats, w, type, hard, sig, chi, diag, sigA, N);

    static const int tilesJ[5] = {10, 6, 6, 3, 3};
    for (int j = 0; j < 5; j++) {
        k_panel<<<dim3(2, B), 256, 0, stream>>>(pos, sigA, diag, C, j);
        if (j == 0)
            k_trail<true><<<dim3(tilesJ[j], B), 256, 0, stream>>>(C, pos, sigA, diag, j);
        else
            k_trail<false><<<dim3(tilesJ[j], B), 256, 0, stream>>>(C, pos, sigA, diag, j);
    }
    k_tail<<<B, 512, 0, stream>>>(C);
    k_solve<<<B, 512, 0, stream>>>(C, chi, Qt, out, B);
}

// Round 9
// 751.013 us; speedup vs baseline: 1.1354x; 1.1354x over previous
//
#include <hip/hip_runtime.h>
#include <math.h>

#define NA 512
#define NN (NA*NA)
#define COULOMB 14.399645478425668f
#define SQRT_PI 1.7724538509055160273f

__device__ __forceinline__ float rl(float x, int lane) {
    return __int_as_float(__builtin_amdgcn_readlane(__float_as_int(x), lane));
}

__device__ __forceinline__ float pair_val(float dx, float dy, float dz,
                                          float s2i, float s2k) {
    float d2 = dx*dx + dy*dy + dz*dz;
    float rinv = rsqrtf(d2);
    return COULOMB * erff(d2 * rinv * rsqrtf(2.f * (s2i + s2k))) * rinv;
}

// ---------------------------------------------------------------- K1: per-atom
__global__ void k_pre(const float* __restrict__ feats, const float* __restrict__ w,
                      const int* __restrict__ type, const float* __restrict__ hard,
                      const float* __restrict__ sigma,
                      float* __restrict__ chi, float* __restrict__ diag,
                      float* __restrict__ sigA, int N) {
    __shared__ float wl[64];
    int tid = threadIdx.x;
    if (tid < 64) wl[tid] = w[tid];
    __syncthreads();
    int i = blockIdx.x * 256 + tid;
    if (i >= N) return;
    const float4* fp = (const float4*)(feats + (size_t)i * 64);
    float acc = 0.f;
#pragma unroll
    for (int q = 0; q < 16; q++) {
        float4 v = fp[q];
        acc += v.x * wl[4*q] + v.y * wl[4*q+1] + v.z * wl[4*q+2] + v.w * wl[4*q+3];
    }
    chi[i] = acc;
    int t = type[i];
    float s = sigma[t];
    float h = hard[t];
    sigA[i] = s;
    diag[i] = h * h + COULOMB / (SQRT_PI * s);
}

// ------------------------------------------- K2: diag factor + split panel trsm (all j)
// 2 blocks per molecule, 256 threads; each block factors the 64x64 diag
// (duplicated) and trsm's half the panel rows. j=7: m=0, factor+store only.
__global__ void __launch_bounds__(256, 1) k_panel(const float* __restrict__ pos,
                                                  const float* __restrict__ sigA,
                                                  const float* __restrict__ diagA,
                                                  float* __restrict__ C, const int j) {
    const int q = blockIdx.x;
    const int b = blockIdx.y;
    float* __restrict__ Cb = C + (size_t)b * NN;
    const int jb = j * 64;
    const int m = NA - jb - 64;
    const int tid = threadIdx.x;
    __shared__ float D[64 * 65];
    __shared__ float DT[64 * 64];
    __shared__ float invd[64];
    __shared__ float px[NA], py[NA], pz[NA], s2s[NA];

    if (j == 0) {
#pragma unroll
        for (int e = 0; e < 2; e++) {
            int i = e * 256 + tid;
            px[i] = pos[((size_t)b * NA + i) * 3 + 0];
            py[i] = pos[((size_t)b * NA + i) * 3 + 1];
            pz[i] = pos[((size_t)b * NA + i) * 3 + 2];
            float s = sigA[b * NA + i];
            s2s[i] = s * s;
        }
        __syncthreads();
    }

#pragma unroll
    for (int e = 0; e < 16; e++) {
        int f = e * 256 + tid;
        int rr = f >> 6, cc = f & 63;
        float v;
        if (j == 0) {
            if (rr == cc) v = diagA[b * NA + rr];
            else v = pair_val(px[rr]-px[cc], py[rr]-py[cc], pz[rr]-pz[cc], s2s[rr], s2s[cc]);
        } else {
            v = Cb[(size_t)(jb + rr) * NA + jb + cc];
        }
        D[rr * 65 + cc] = v;
    }

    const int h = m >> 1;
    const int r0 = q ? h : 0;
    const int nr = q ? (m - h) : h;
    const int r = tid - 32;
    const bool hasrow = (r >= 0 && r < nr);
    const int grow = jb + 64 + r0 + r;
    float rv[64];
    if (hasrow) {
        if (j == 0) {
#pragma unroll
            for (int k = 0; k < 64; k++)
                rv[k] = pair_val(px[grow]-px[k], py[grow]-py[k], pz[grow]-pz[k],
                                 s2s[grow], s2s[k]);
        } else {
            const float4* rp = (const float4*)(Cb + (size_t)grow * NA + jb);
#pragma unroll
            for (int qq = 0; qq < 16; qq++) {
                float4 v = rp[qq];
                rv[4*qq] = v.x; rv[4*qq+1] = v.y; rv[4*qq+2] = v.z; rv[4*qq+3] = v.w;
            }
        }
    }
    __syncthreads();

    if (tid < 64) {
        const int t = tid;
        float cl[64];
#pragma unroll
        for (int i = 0; i < 64; i++) cl[i] = (i >= t) ? D[i * 65 + t] : D[t * 65 + i];
#pragma unroll
        for (int k = 0; k < 64; k++) {
            float pivot = rl(cl[k], k);
            float invp = 1.0f / pivot;
            float factor = (t > k) ? (cl[k] * invp) : 0.0f;
#pragma unroll
            for (int i = k + 1; i < 64; i++) {
                float bc = rl(cl[i], k);
                cl[i] -= bc * factor;
            }
        }
        float rs = 1.0f / sqrtf(cl[t]);
        invd[t] = rs;
#pragma unroll
        for (int i = 0; i < 64; i++)
            if (i >= t) D[i * 65 + t] = cl[i] * rs;
    }
    __syncthreads();

#pragma unroll
    for (int e = 0; e < 16; e++) {
        int f = e * 256 + tid;
        int row = f >> 6, cc = f & 63;
        float v = D[row * 65 + cc];
        DT[row * 64 + cc] = (cc < row) ? v : 0.f;
        if (q == 0 && cc <= row) Cb[(size_t)(jb + row) * NA + jb + cc] = v;
    }
    __syncthreads();

    if (hasrow) {
#pragma unroll
        for (int k = 0; k < 64; k++) {
            float acc = rv[k];
            const float4* Lr = (const float4*)(DT + k * 64);
            const int k4 = k >> 2;
#pragma unroll
            for (int t4 = 0; t4 < k4; t4++) {
                float4 Lv = Lr[t4];
                acc -= Lv.x * rv[4*t4] + Lv.y * rv[4*t4+1] + Lv.z * rv[4*t4+2] + Lv.w * rv[4*t4+3];
            }
#pragma unroll
            for (int tt = k4 * 4; tt < k; tt++) acc -= DT[k * 64 + tt] * rv[tt];
            rv[k] = acc * invd[k];
        }
        float4* rp = (float4*)(Cb + (size_t)grow * NA + jb);
#pragma unroll
        for (int qq = 0; qq < 16; qq++)
            rp[qq] = make_float4(rv[4*qq], rv[4*qq+1], rv[4*qq+2], rv[4*qq+3]);
    }
}

// ------------------------------------------- K3: trailing update (all j) — round-3 proven
template<bool GEN>
__global__ void __launch_bounds__(256, 3) k_trail(float* __restrict__ C,
                                                  const float* __restrict__ pos,
                                                  const float* __restrict__ sigA,
                                                  const float* __restrict__ diagA,
                                                  const int j) {
    const int b = blockIdx.y;
    float* __restrict__ Cb = C + (size_t)b * NN;
    const int jb = j * 64;
    const int m = NA - jb - 64;
    int t = blockIdx.x;
    int RI = 0;
    while (t >= RI + 1) { t -= RI + 1; RI++; }
    const int RJ = t;
    const int RB = RI * 128, CB = RJ * 128;
    const int vr = min(128, m - RB);
    const int vc = min(128, m - CB);
    const int tid = threadIdx.x;
    const int rg = tid >> 4, cg = tid & 15;

    __shared__ float As[128 * 65];
    __shared__ float Bs[128 * 65];

    float acc[8][8];

    if (GEN) {
        __shared__ float pAx[128], pAy[128], pAz[128], sA[128], dA[128];
        __shared__ float pBx[128], pBy[128], pBz[128], sB[128];
        if (tid < 128) {
            if (RB + tid < m) {
                int ga = b * NA + jb + 64 + RB + tid;
                pAx[tid] = pos[(size_t)ga * 3 + 0];
                pAy[tid] = pos[(size_t)ga * 3 + 1];
                pAz[tid] = pos[(size_t)ga * 3 + 2];
                float s = sigA[ga]; sA[tid] = s * s;
                dA[tid] = diagA[ga];
            }
        } else {
            int u = tid - 128;
            if (CB + u < m) {
                int gb = b * NA + jb + 64 + CB + u;
                pBx[u] = pos[(size_t)gb * 3 + 0];
                pBy[u] = pos[(size_t)gb * 3 + 1];
                pBz[u] = pos[(size_t)gb * 3 + 2];
                float s = sigA[gb]; sB[u] = s * s;
            }
        }
        __syncthreads();
#pragma unroll
        for (int rr = 0; rr < 8; rr++) {
            int row = rg * 8 + rr;
#pragma unroll
            for (int cc = 0; cc < 8; cc++) {
                int col = cg + 16 * cc;
                if (RB + row == CB + col)
                    acc[rr][cc] = dA[row];
                else
                    acc[rr][cc] = pair_val(pAx[row]-pBx[col], pAy[row]-pBy[col],
                                           pAz[row]-pBz[col], sA[row], sB[col]);
            }
        }
        __syncthreads();
    } else {
        const int GRB = jb + 64 + RB, GCB = jb + 64 + CB;
#pragma unroll
        for (int rr = 0; rr < 8; rr++) {
            int row = rg * 8 + rr;
#pragma unroll
            for (int cc = 0; cc < 8; cc++) {
                int col = cg + 16 * cc;
                acc[rr][cc] = (row < vr && col < vc)
                    ? Cb[(size_t)(GRB + row) * NA + GCB + col] : 0.f;
            }
        }
    }

    const float* Pan = Cb + (size_t)(jb + 64) * NA + jb;
#pragma unroll
    for (int e = 0; e < 8; e++) {
        int f = e * 256 + tid;
        int row = f >> 4, s = f & 15;
        float4 v = make_float4(0.f, 0.f, 0.f, 0.f);
        if (row < vr) v = *(const float4*)(Pan + (size_t)(RB + row) * NA + s * 4);
        As[row * 65 + s * 4 + 0] = v.x;
        As[row * 65 + s * 4 + 1] = v.y;
        As[row * 65 + s * 4 + 2] = v.z;
        As[row * 65 + s * 4 + 3] = v.w;
        float4 u = make_float4(0.f, 0.f, 0.f, 0.f);
        if (row < vc) u = *(const float4*)(Pan + (size_t)(CB + row) * NA + s * 4);
        Bs[row * 65 + s * 4 + 0] = u.x;
        Bs[row * 65 + s * 4 + 1] = u.y;
        Bs[row * 65 + s * 4 + 2] = u.z;
        Bs[row * 65 + s * 4 + 3] = u.w;
    }
    __syncthreads();

#pragma unroll 4
    for (int k = 0; k < 64; k++) {
        float ai[8], bj[8];
#pragma unroll
        for (int rr = 0; rr < 8; rr++) ai[rr] = As[(rg * 8 + rr) * 65 + k];
#pragma unroll
        for (int cc = 0; cc < 8; cc++) bj[cc] = Bs[(cg + 16 * cc) * 65 + k];
#pragma unroll
        for (int rr = 0; rr < 8; rr++)
#pragma unroll
            for (int cc = 0; cc < 8; cc++)
                acc[rr][cc] = fmaf(-ai[rr], bj[cc], acc[rr][cc]);
    }

    const int GRB = jb + 64 + RB, GCB = jb + 64 + CB;
#pragma unroll
    for (int rr = 0; rr < 8; rr++) {
        int row = rg * 8 + rr;
        if (row < vr) {
#pragma unroll
            for (int cc = 0; cc < 8; cc++) {
                int col = cg + 16 * cc;
                if (col < vc)
                    Cb[(size_t)(GRB + row) * NA + GCB + col] = acc[rr][cc];
            }
        }
    }
}

// ------------------------------------------- K5: solve + outputs (round-4 proven)
__global__ void __launch_bounds__(512, 1) k_solve(const float* __restrict__ C,
                                                  const float* __restrict__ chiA,
                                                  const float* __restrict__ Qtot,
                                                  float* __restrict__ out, int B) {
    int b = blockIdx.x;
    const float* Cb = C + (size_t)b * NN;
    int tid = threadIdx.x;
    __shared__ float D[64 * 65];
    __shared__ float r1[NA], r2[NA];
    __shared__ float pb1[4][NA], pb2[4][NA];
    __shared__ float red[16];
    __shared__ float muS;

    r1[tid] = chiA[b * NA + tid];
    r2[tid] = 1.0f;

    const int sub = tid & 7;
    const int rowg = tid >> 3;

    for (int j = 0; j < 8; j++) {
        const int jb = j * 64;
        __syncthreads();
#pragma unroll
        for (int e = 0; e < 8; e++) {
            int f = e * 512 + tid;
            int row = f >> 6, cc = f & 63;
            D[row * 65 + cc] = Cb[(size_t)(jb + row) * NA + jb + cc];
        }
        __syncthreads();
        if (tid < 128) {
            int lane = tid & 63;
            float* vv = (tid < 64) ? r1 : r2;
            float val = vv[jb + lane];
            float idg = 1.0f / D[lane * 65 + lane];
#pragma unroll
            for (int k = 0; k < 64; k++) {
                float yk = rl(val, k) * rl(idg, k);
                if (lane == k) vv[jb + k] = yk;
                float lv = (lane > k) ? D[lane * 65 + k] : 0.f;
                val -= lv * yk;
            }
        }
        __syncthreads();
#pragma unroll
        for (int p = 0; p < 7; p++) {
            int g = jb + 64 + p * 64 + rowg;
            if (g < NA) {
                const float4* Lr = (const float4*)(Cb + (size_t)g * NA + jb + sub * 8);
                float4 a0 = Lr[0], a1 = Lr[1];
                int y0 = jb + sub * 8;
                float d1 = a0.x*r1[y0]   + a0.y*r1[y0+1] + a0.z*r1[y0+2] + a0.w*r1[y0+3]
                         + a1.x*r1[y0+4] + a1.y*r1[y0+5] + a1.z*r1[y0+6] + a1.w*r1[y0+7];
                float d2 = a0.x*r2[y0]   + a0.y*r2[y0+1] + a0.z*r2[y0+2] + a0.w*r2[y0+3]
                         + a1.x*r2[y0+4] + a1.y*r2[y0+5] + a1.z*r2[y0+6] + a1.w*r2[y0+7];
                d1 += __shfl_xor(d1, 1); d2 += __shfl_xor(d2, 1);
                d1 += __shfl_xor(d1, 2); d2 += __shfl_xor(d2, 2);
                d1 += __shfl_xor(d1, 4); d2 += __shfl_xor(d2, 4);
                if (sub == 0) { r1[g] -= d1; r2[g] -= d2; }
            }
        }
    }

    const int ii = tid & 127;
    const int gg = tid >> 7;
    for (int j = 7; j >= 0; j--) {
        const int jb = j * 64;
        __syncthreads();
#pragma unroll
        for (int e = 0; e < 8; e++) {
            int f = e * 512 + tid;
            int row = f >> 6, cc = f & 63;
            D[row * 65 + cc] = Cb[(size_t)(jb + row) * NA + jb + cc];
        }
        __syncthreads();
        if (tid < 128) {
            int lane = tid & 63;
            float* vv = (tid < 64) ? r1 : r2;
            float val = vv[jb + lane];
            float idg = 1.0f / D[lane * 65 + lane];
#pragma unroll
            for (int k = 63; k >= 0; k--) {
                float xk = rl(val, k) * rl(idg, k);
                if (lane == k) vv[jb + k] = xk;
                float lv = (lane < k) ? D[k * 65 + lane] : 0.f;
                val -= lv * xk;
            }
        }
        __syncthreads();
        if (jb > 0) {
            const int nf4 = jb >> 2;
            float4 s1 = make_float4(0.f,0.f,0.f,0.f), s2 = make_float4(0.f,0.f,0.f,0.f);
            if (ii < nf4) {
#pragma unroll
                for (int gq = 0; gq < 16; gq++) {
                    int g = jb + gg * 16 + gq;
                    float x1 = r1[g], x2 = r2[g];
                    float4 Lv = *(const float4*)(Cb + (size_t)g * NA + ii * 4);
                    s1.x += Lv.x * x1; s1.y += Lv.y * x1; s1.z += Lv.z * x1; s1.w += Lv.w * x1;
                    s2.x += Lv.x * x2; s2.y += Lv.y * x2; s2.z += Lv.z * x2; s2.w += Lv.w * x2;
                }
            }
            *(float4*)(&pb1[gg][ii * 4]) = s1;
            *(float4*)(&pb2[gg][ii * 4]) = s2;
            __syncthreads();
            if (tid < jb) {
                r1[tid] -= pb1[0][tid] + pb1[1][tid] + pb1[2][tid] + pb1[3][tid];
                r2[tid] -= pb2[0][tid] + pb2[1][tid] + pb2[2][tid] + pb2[3][tid];
            }
        }
    }
    __syncthreads();

    float s1p = r1[tid], s2p = r2[tid];
#pragma unroll
    for (int off = 1; off < 64; off <<= 1) {
        s1p += __shfl_xor(s1p, off);
        s2p += __shfl_xor(s2p, off);
    }
    if ((tid & 63) == 0) { red[tid >> 6] = s1p; red[8 + (tid >> 6)] = s2p; }
    __syncthreads();
    if (tid == 0) {
        float s1 = 0.f, s2 = 0.f;
#pragma unroll
        for (int wv = 0; wv < 8; wv++) { s1 += red[wv]; s2 += red[8 + wv]; }
        muS = -(Qtot[b] + s1) / s2;
    }
    __syncthreads();
    float mu = muS;
    float qv = -r1[tid] - mu * r2[tid];
    out[B + (size_t)b * NA + tid] = qv;

    float eacc = chiA[b * NA + tid] * qv;
#pragma unroll
    for (int off = 1; off < 64; off <<= 1) eacc += __shfl_xor(eacc, off);
    __syncthreads();
    if ((tid & 63) == 0) red[tid >> 6] = eacc;
    __syncthreads();
    if (tid == 0) {
        float e = 0.f;
#pragma unroll
        for (int wv = 0; wv < 8; wv++) e += red[wv];
        out[b] = 0.5f * e - 0.5f * mu * Qtot[b];
    }
}

// ---------------------------------------------------------------- host launch
extern "C" void kernel_launch(void* const* d_in, const int* in_sizes, int n_in,
                              void* d_out, int out_size, void* d_ws, size_t ws_size,
                              hipStream_t stream) {
    const int B = in_sizes[3];          // 128 molecules
    const int N = in_sizes[2];          // 65536 atoms
    const float* feats = (const float*)d_in[0];
    const float* pos   = (const float*)d_in[1];
    const int*   type  = (const int*)d_in[2];
    const float* Qt    = (const float*)d_in[3];
    const float* w     = (const float*)d_in[4];
    const float* hard  = (const float*)d_in[5];
    const float* sig   = (const float*)d_in[6];
    float* out = (float*)d_out;
    float* ws  = (float*)d_ws;

    float* C    = ws;                       // B * 512 * 512
    float* chi  = ws + (size_t)B * NN;      // N
    float* diag = chi + N;                  // N
    float* sigA = diag + N;                 // N

    k_pre<<<(N + 255) / 256, 256, 0, stream>>>(feats, w, type, hard, sig, chi, diag, sigA, N);

    static const int tilesJ[7] = {10, 6, 6, 3, 3, 1, 1};
    for (int j = 0; j < 8; j++) {
        k_panel<<<dim3(2, B), 256, 0, stream>>>(pos, sigA, diag, C, j);
        if (j < 7) {
            if (j == 0)
                k_trail<true><<<dim3(tilesJ[j], B), 256, 0, stream>>>(C, pos, sigA, diag, j);
            else
                k_trail<false><<<dim3(tilesJ[j], B), 256, 0, stream>>>(C, pos, sigA, diag, j);
        }
    }
    k_solve<<<B, 512, 0, stream>>>(C, chi, Qt, out, B);
}